// Round 4
// baseline (14380.103 us; speedup 1.0000x reference)
//
#include <hip/hip_runtime.h>
#include <hip/hip_fp16.h>
#include <math.h>
#include <type_traits>

#define D 2048
#define NH 8
#define DH 256
#define TT 256
#define BT 8192        // B*T rows
#define LNEPS 1e-5f

// ---------------------------------------------------------------- GEMM
// C[M,N] = act(LN?(A)[M,K] @ W[K,N] + bias) (+res)
// EPI: 0 = bias, 1 = bias+gelu, 2 = bias+residual, 3 = residual only (no bias)
// LNA: 1 = apply LayerNorm(lng,lnb) to A rows during staging (AT must be float)
// AT: A dtype (float or __half).  OT: output dtype (float or __half).
// ldw: leading dimension (row stride) of W; N is the logical slice width of
//      W/bias/C/res for this launch.
#define BM 64
#define BN 64
#define BK 32

__device__ __forceinline__ float gelu_exact(float x) {
    return 0.5f * x * (1.f + erff(x * 0.70710678118654752f));
}

template <int EPI, int LNA, typename AT, typename OT>
__global__ __launch_bounds__(256) void gemm_kernel(const AT* __restrict__ A,
                                                   const float* __restrict__ W,
                                                   const float* __restrict__ bias,
                                                   const float* __restrict__ res,
                                                   const float* __restrict__ lng,
                                                   const float* __restrict__ lnb,
                                                   OT* __restrict__ C,
                                                   int M, int N, int K, int ldw) {
    __shared__ float As[BK][BM + 4];   // transposed: As[k][m]
    __shared__ float Bs[BK][BN + 4];   // Bs[k][n]
    __shared__ float rowm[BM], rowr[BM];
    int tid = threadIdx.x;

    // XCD-aware bijective swizzle (all our grids have nwg % 8 == 0):
    // hw block b lands on XCD b%8; give each XCD a contiguous logical chunk
    // (row-major over bn so same-bm panels share that XCD's L2).
    int nwg = gridDim.x * gridDim.y;
    int b = blockIdx.x + gridDim.x * blockIdx.y;
    int chunk = nwg >> 3;
    int logical = (b & 7) * chunk + (b >> 3);
    int bn = logical % gridDim.x;
    int bm = logical / gridDim.x;

    int tm = tid >> 4, tn = tid & 15;          // 16x16 threads, 4x4 each
    const AT* Ab = A + (size_t)bm * BM * K;
    const float* Wb = W + (size_t)bn * BN;

    if constexpr (LNA) {
        // Row-stats pre-pass: 4 threads per row, each streams K/4 floats.
        int r = tid >> 2, seg = tid & 3;
        const float* xr = (const float*)Ab + (size_t)r * K + seg * (K >> 2);
        float s = 0.f, sq = 0.f;
        for (int c = 0; c < (K >> 2); c += 4) {
            float4 v = *(const float4*)(xr + c);
            s  += v.x + v.y + v.z + v.w;
            sq += v.x * v.x + v.y * v.y + v.z * v.z + v.w * v.w;
        }
        s  += __shfl_xor(s, 1);  s  += __shfl_xor(s, 2);
        sq += __shfl_xor(sq, 1); sq += __shfl_xor(sq, 2);
        if (seg == 0) {
            float mean = s * (1.f / K);
            rowm[r] = mean;
            rowr[r] = rsqrtf(sq * (1.f / K) - mean * mean + LNEPS);
        }
        __syncthreads();
    }

    float acc[4][4] = {};

    for (int k0 = 0; k0 < K; k0 += BK) {
        // ---- stage A ----
        if constexpr (std::is_same<AT, float>::value) {
            #pragma unroll
            for (int i = 0; i < 2; i++) {
                int f = tid + i * 256;             // 0..511: 64 rows x 8 float4
                int r = f >> 3, c4 = f & 7;
                float4 a4 = *(const float4*)((const float*)Ab + (size_t)r * K + k0 + c4 * 4);
                if constexpr (LNA) {
                    float mu = rowm[r], rs = rowr[r];
                    float4 g4 = *(const float4*)(lng + k0 + c4 * 4);
                    float4 b4 = *(const float4*)(lnb + k0 + c4 * 4);
                    a4.x = (a4.x - mu) * rs * g4.x + b4.x;
                    a4.y = (a4.y - mu) * rs * g4.y + b4.y;
                    a4.z = (a4.z - mu) * rs * g4.z + b4.z;
                    a4.w = (a4.w - mu) * rs * g4.w + b4.w;
                }
                As[c4 * 4 + 0][r] = a4.x;
                As[c4 * 4 + 1][r] = a4.y;
                As[c4 * 4 + 2][r] = a4.z;
                As[c4 * 4 + 3][r] = a4.w;
            }
        } else {
            int f = tid;                           // 256: 64 rows x 4 chunks of 8 halves
            int r = f >> 2, c8 = f & 3;
            const __half2* hp = (const __half2*)((const __half*)Ab + (size_t)r * K + k0 + c8 * 8);
            uint4 raw = *(const uint4*)hp;
            const __half2* h2 = (const __half2*)&raw;
            #pragma unroll
            for (int i = 0; i < 4; i++) {
                float2 f2 = __half22float2(h2[i]);
                As[c8 * 8 + 2 * i + 0][r] = f2.x;
                As[c8 * 8 + 2 * i + 1][r] = f2.y;
            }
        }
        // ---- stage B (fp32 weights, row stride ldw) ----
        #pragma unroll
        for (int i = 0; i < 2; i++) {
            int f = tid + i * 256;                 // 0..511: 32 rows x 16 float4
            int rb = f >> 4, cb = f & 15;
            float4 b4 = *(const float4*)(Wb + (size_t)(k0 + rb) * ldw + cb * 4);
            *((float4*)&Bs[rb][cb * 4]) = b4;
        }
        __syncthreads();
        #pragma unroll
        for (int kk = 0; kk < BK; kk++) {
            float4 a = *((const float4*)&As[kk][tm * 4]);
            float4 bb4 = *((const float4*)&Bs[kk][tn * 4]);
            acc[0][0] += a.x * bb4.x; acc[0][1] += a.x * bb4.y; acc[0][2] += a.x * bb4.z; acc[0][3] += a.x * bb4.w;
            acc[1][0] += a.y * bb4.x; acc[1][1] += a.y * bb4.y; acc[1][2] += a.y * bb4.z; acc[1][3] += a.y * bb4.w;
            acc[2][0] += a.z * bb4.x; acc[2][1] += a.z * bb4.y; acc[2][2] += a.z * bb4.z; acc[2][3] += a.z * bb4.w;
            acc[3][0] += a.w * bb4.x; acc[3][1] += a.w * bb4.y; acc[3][2] += a.w * bb4.z; acc[3][3] += a.w * bb4.w;
        }
        __syncthreads();
    }

    int col = bn * BN + tn * 4;
    float4 bi = make_float4(0.f, 0.f, 0.f, 0.f);
    if constexpr (EPI != 3) bi = *(const float4*)(bias + col);
    #pragma unroll
    for (int i = 0; i < 4; i++) {
        int row = bm * BM + tm * 4 + i;
        float4 o;
        o.x = acc[i][0] + bi.x;
        o.y = acc[i][1] + bi.y;
        o.z = acc[i][2] + bi.z;
        o.w = acc[i][3] + bi.w;
        if constexpr (EPI == 1) {
            o.x = gelu_exact(o.x); o.y = gelu_exact(o.y);
            o.z = gelu_exact(o.z); o.w = gelu_exact(o.w);
        }
        if constexpr (EPI == 2 || EPI == 3) {
            float4 r4 = *(const float4*)(res + (size_t)row * N + col);
            o.x += r4.x; o.y += r4.y; o.z += r4.z; o.w += r4.w;
        }
        if constexpr (std::is_same<OT, float>::value) {
            *(float4*)((float*)C + (size_t)row * N + col) = o;
        } else {
            union { __half2 h2[2]; uint2 u; } pk;
            pk.h2[0] = __floats2half2_rn(o.x, o.y);
            pk.h2[1] = __floats2half2_rn(o.z, o.w);
            *(uint2*)((__half*)C + (size_t)row * N + col) = pk.u;
        }
    }
}

// ---------------------------------------------------------------- Attention
// Flash-style causal attention. Block = one (batch, head, 64-query tile).
// 256 threads: thread (ql, p) with ql=tid>>2 (query), p=tid&3 owns dims {p+4j}.
#define QB 64
#define KB 32
#define KSTR 264   // 32-row K/V LDS tile row stride (floats); 264*4B % 16B == 0
#define PSTR 36

template <typename T>
__global__ __launch_bounds__(256) void attn_kernel(const T* __restrict__ q,
                                                   const T* __restrict__ k,
                                                   const T* __restrict__ v,
                                                   float* __restrict__ out) {
    __shared__ float kv[KB][KSTR];
    __shared__ float ps[QB][PSTR];
    int tid = threadIdx.x;

    // XCD swizzle: keep the 4 causal q-tiles of one (batch,head) on one XCD
    // so they share that head's K/V in its L2. 1024 blocks, %8==0.
    int bsw = blockIdx.x;
    int logical = (bsw & 7) * 128 + (bsw >> 3);
    int qt = logical & 3;
    int hh = (logical >> 2) & 7;
    int bb = logical >> 5;
    const size_t bh_off = (size_t)bb * (TT * D) + hh * DH;

    int ql = tid >> 2;       // 0..63
    int p  = tid & 3;        // 0..3
    int qg = qt * QB + ql;   // global query row

    float qreg[64];
    float acc[64];
    #pragma unroll
    for (int j = 0; j < 64; j++) acc[j] = 0.f;
    float m = -INFINITY, l = 0.f;

    // Stage one 32-row tile (rows rbase..rbase+31 of src) into kv.
    auto stage = [&](const T* src, int rbase) {
        if constexpr (std::is_same<T, float>::value) {
            for (int f = tid; f < KB * 64; f += 256) {
                int r = f >> 6, c4 = f & 63;
                *((float4*)&kv[r][c4 * 4]) =
                    *(const float4*)(src + bh_off + (size_t)(rbase + r) * D + c4 * 4);
            }
        } else {
            for (int f = tid; f < KB * 32; f += 256) {
                int r = f >> 5, c8 = f & 31;
                uint4 raw = *(const uint4*)(src + bh_off + (size_t)(rbase + r) * D + c8 * 8);
                const __half2* h2 = (const __half2*)&raw;
                #pragma unroll
                for (int i = 0; i < 4; i++) {
                    float2 f2 = __half22float2(h2[i]);
                    kv[r][c8 * 8 + 2 * i + 0] = f2.x;
                    kv[r][c8 * 8 + 2 * i + 1] = f2.y;
                }
            }
        }
    };

    // stage Q tile through kv buffer (2 halves of 32 rows), coalesced
    for (int half = 0; half < 2; half++) {
        stage(q, qt * QB + half * KB);
        __syncthreads();
        if ((ql >> 5) == half) {
            int r = ql & 31;
            #pragma unroll
            for (int j = 0; j < 64; j++) qreg[j] = kv[r][p + 4 * j];
        }
        __syncthreads();
    }

    int ntiles = 2 * qt + 2;
    for (int t = 0; t < ntiles; t++) {
        int s0 = t * KB;
        stage(k, s0);
        __syncthreads();
        // scores: thread (ql,p) partial-dots over its 64 dims, reduce over p
        for (int s = 0; s < KB; s++) {
            float part = 0.f;
            #pragma unroll
            for (int j = 0; j < 64; j++) part += qreg[j] * kv[s][p + 4 * j];
            part += __shfl_xor(part, 1);
            part += __shfl_xor(part, 2);
            if (p == 0) {
                bool valid = (s0 + s) <= qg;
                ps[ql][s] = valid ? part * 0.0625f : -INFINITY;
            }
        }
        __syncthreads();
        // online-softmax stats (each p-thread redundantly; identical results)
        float tmax = -INFINITY;
        #pragma unroll
        for (int s = 0; s < KB; s++) tmax = fmaxf(tmax, ps[ql][s]);
        float mn = fmaxf(m, tmax);           // tile 0 always has a valid key
        float alpha = expf(m - mn);
        #pragma unroll
        for (int j = 0; j < 64; j++) acc[j] *= alpha;
        // load V tile (overwrites K; all K reads completed before last sync)
        stage(v, s0);
        __syncthreads();
        float sum = 0.f;
        for (int s = 0; s < KB; s++) {
            float e = expf(ps[ql][s] - mn);  // masked -> exp(-inf) = 0
            sum += e;
            #pragma unroll
            for (int j = 0; j < 64; j++) acc[j] += e * kv[s][p + 4 * j];
        }
        l = l * alpha + sum;
        m = mn;
        __syncthreads();
    }

    float inv = 1.f / l;
    #pragma unroll
    for (int j = 0; j < 64; j++)
        out[bh_off + (size_t)qg * D + p + 4 * j] = acc[j] * inv;
}

// ---------------------------------------------------------------- launch
// Workspace-adaptive (round-2 SIGABRT suspected d_ws overflow at 403 MB):
//   Plan A (ws >= 192 MiB): fp32 q/k/v slots; x1 overlays q; fp16 u overlays
//                           k+v; att scratch in d_out. 7 dispatches.
//   Plan B (ws >= 128 MiB): fp16 q/k/v (96 MiB); x1 overlays q+k; fp16 u-half
//                           (64 MiB) at [64,128) MiB; MLP in 2 sliced chunks
//                           with residual-only accumulate. 9 dispatches.
extern "C" void kernel_launch(void* const* d_in, const int* in_sizes, int n_in,
                              void* d_out, int out_size, void* d_ws, size_t ws_size,
                              hipStream_t stream) {
    const float* x    = (const float*)d_in[0];
    const float* ln1g = (const float*)d_in[1];
    const float* ln1b = (const float*)d_in[2];
    const float* wq   = (const float*)d_in[3];
    const float* bq   = (const float*)d_in[4];
    const float* wk   = (const float*)d_in[5];
    const float* bk   = (const float*)d_in[6];
    const float* wv   = (const float*)d_in[7];
    const float* bv   = (const float*)d_in[8];
    const float* wo   = (const float*)d_in[9];
    const float* bo   = (const float*)d_in[10];
    const float* ln2g = (const float*)d_in[11];
    const float* ln2b = (const float*)d_in[12];
    const float* w1   = (const float*)d_in[13];
    const float* b1   = (const float*)d_in[14];
    const float* w2   = (const float*)d_in[15];
    const float* b2   = (const float*)d_in[16];

    float* ws = (float*)d_ws;
    const size_t NTD = (size_t)BT * D;   // 16.7M elements; 64 MiB as fp32
    float* att = (float*)d_out;          // attention scratch lives in d_out
    float* out = (float*)d_out;

    dim3 blk(256);
    dim3 gQKV(D / BN, BT / BM);          // (32,128)
    dim3 gMLP1A(4 * D / BN, BT / BM);    // (128,128)
    dim3 gMLP1B(2 * D / BN, BT / BM);    // (64,128)

    if (ws_size >= ((size_t)192 << 20)) {
        // ---------------- Plan A ----------------
        float* qb  = ws;               // slot0: q, later x1
        float* kb  = ws + NTD;         // slot1
        float* vb  = ws + 2 * NTD;     // slot2
        float* x1  = qb;
        __half* u  = (__half*)kb;      // fp16 MLP intermediate overlays k+v

        gemm_kernel<0, 1, float, float><<<gQKV, blk, 0, stream>>>(
            x, wq, bq, nullptr, ln1g, ln1b, qb, BT, D, D, D);
        gemm_kernel<0, 1, float, float><<<gQKV, blk, 0, stream>>>(
            x, wk, bk, nullptr, ln1g, ln1b, kb, BT, D, D, D);
        gemm_kernel<0, 1, float, float><<<gQKV, blk, 0, stream>>>(
            x, wv, bv, nullptr, ln1g, ln1b, vb, BT, D, D, D);
        attn_kernel<float><<<32 * 8 * 4, blk, 0, stream>>>(qb, kb, vb, att);
        gemm_kernel<2, 0, float, float><<<gQKV, blk, 0, stream>>>(
            att, wo, bo, x, nullptr, nullptr, x1, BT, D, D, D);
        gemm_kernel<1, 1, float, __half><<<gMLP1A, blk, 0, stream>>>(
            x1, w1, b1, nullptr, ln2g, ln2b, u, BT, 4 * D, D, 4 * D);
        gemm_kernel<2, 0, __half, float><<<gQKV, blk, 0, stream>>>(
            u, w2, b2, x1, nullptr, nullptr, out, BT, D, 4 * D, D);
    } else {
        // ---------------- Plan B ----------------
        __half* qh = (__half*)ws;            // [0, 32 MiB)
        __half* kh = qh + NTD;               // [32, 64)
        __half* vh = kh + NTD;               // [64, 96)
        float*  x1 = ws;                     // [0, 64) overlays qh+kh (dead)
        __half* u  = (__half*)ws + 2 * NTD;  // [64, 128) overlays vh (dead)

        gemm_kernel<0, 1, float, __half><<<gQKV, blk, 0, stream>>>(
            x, wq, bq, nullptr, ln1g, ln1b, qh, BT, D, D, D);
        gemm_kernel<0, 1, float, __half><<<gQKV, blk, 0, stream>>>(
            x, wk, bk, nullptr, ln1g, ln1b, kh, BT, D, D, D);
        gemm_kernel<0, 1, float, __half><<<gQKV, blk, 0, stream>>>(
            x, wv, bv, nullptr, ln1g, ln1b, vh, BT, D, D, D);
        attn_kernel<__half><<<32 * 8 * 4, blk, 0, stream>>>(qh, kh, vh, att);
        gemm_kernel<2, 0, float, float><<<gQKV, blk, 0, stream>>>(
            att, wo, bo, x, nullptr, nullptr, x1, BT, D, D, D);
        // MLP in two 4096-wide chunks; chunk1 accumulates into out.
        gemm_kernel<1, 1, float, __half><<<gMLP1B, blk, 0, stream>>>(
            x1, w1, b1, nullptr, ln2g, ln2b, u, BT, 2 * D, D, 4 * D);
        gemm_kernel<2, 0, __half, float><<<gQKV, blk, 0, stream>>>(
            u, w2, b2, x1, nullptr, nullptr, out, BT, D, 2 * D, D);
        gemm_kernel<1, 1, float, __half><<<gMLP1B, blk, 0, stream>>>(
            x1, w1 + 2 * D, b1 + 2 * D, nullptr, ln2g, ln2b, u, BT, 2 * D, D, 4 * D);
        gemm_kernel<3, 0, __half, float><<<gQKV, blk, 0, stream>>>(
            u, w2 + (size_t)(2 * D) * D, nullptr, out, nullptr, nullptr, out, BT, D, 2 * D, D);
    }
}